// Round 1
// baseline (323.529 us; speedup 1.0000x reference)
//
#include <hip/hip_runtime.h>
#include <math.h>

#define BB 32
#define CC 256
#define HH 56
#define WW 56
#define KP 49      // 7*7 output pixels of the small convs
#define CMID 64    // C // RED
#define HW 3136    // 56*56

// dwconv LDS plane geometry: 62 padded rows, 64-word ring per row
#define RSTR 64
#define PROWS 62
#define PSZ (PROWS * RSTR)   // 3968 words per plane

// -------- K0: transpose weights to channel-last for lane=cout coalescing -----
__global__ __launch_bounds__(256) void transpose_w_kernel(const float* __restrict__ w1,
                                                          const float* __restrict__ w2,
                                                          float* __restrict__ w1t,
                                                          float* __restrict__ w2t) {
    int tid = blockIdx.x * 256 + threadIdx.x;
    if (tid < 147456) {
        int co = tid & 63, ct = tid >> 6;
        w1t[tid] = w1[co * 2304 + ct];
    }
    if (tid < 294912) {
        int co = tid & 511, ct = tid >> 9;
        w2t[tid] = w2[co * 576 + ct];
    }
}

// ------------- K1: adaptive avg pool, no LDS: wave = plane, lane = window -----
__global__ __launch_bounds__(256) void pool_kernel(const float* __restrict__ x,
                                                   float* __restrict__ pooled) {
    int wv = threadIdx.x >> 6, lane = threadIdx.x & 63;
    int g = blockIdx.x * 4 + wv;            // plane id = b*256 + c
    if (lane < KP) {
        int ko = lane / 7, kw = lane - ko * 7;
        const float* base = x + (size_t)g * HW + (ko * 8) * WW + kw * 8;
        float s = 0.f;
        #pragma unroll
        for (int r = 0; r < 8; ++r) {
            float4 a = *(const float4*)(base + r * WW);
            float4 b4 = *(const float4*)(base + r * WW + 4);
            s += a.x + a.y + a.z + a.w + b4.x + b4.y + b4.z + b4.w;
        }
        pooled[(size_t)g * KP + lane] = s * (1.f / 64.f);
    }
}

// ------------- K2: conv3x3 (256->64) + BN + exact GELU; 512 thr, 8-way cin ---
__global__ __launch_bounds__(512) void conv1_kernel(const float* __restrict__ pooled,
                                                    const float* __restrict__ w1t,
                                                    const float* __restrict__ gamma,
                                                    const float* __restrict__ beta,
                                                    float* __restrict__ hmid) {
    int y = blockIdx.x, b = blockIdx.y;
    int wv = threadIdx.x >> 6, co = threadIdx.x & 63;
    __shared__ float red[8][7][64];
    float acc[7] = {0.f, 0.f, 0.f, 0.f, 0.f, 0.f, 0.f};
    const float* pb = pooled + (size_t)b * CC * KP;
    for (int ci = 0; ci < 32; ++ci) {
        int cin = wv * 32 + ci;
        const float* prow_base = pb + cin * KP;
        const float* wbase = w1t + (size_t)(cin * 9) * 64 + co;
        #pragma unroll
        for (int ky = 0; ky < 3; ++ky) {
            int iy = y + ky - 1;
            if (0 <= iy && iy < 7) {                    // uniform branch
                float s[9];
                s[0] = 0.f; s[8] = 0.f;
                const float* pr = prow_base + iy * 7;   // uniform addr -> s_load
                #pragma unroll
                for (int j = 0; j < 7; ++j) s[j + 1] = pr[j];
                const float* wr = wbase + ky * 3 * 64;
                float w0 = wr[0], w1v = wr[64], w2v = wr[128];
                #pragma unroll
                for (int xx = 0; xx < 7; ++xx)
                    acc[xx] += s[xx] * w0 + s[xx + 1] * w1v + s[xx + 2] * w2v;
            }
        }
    }
    #pragma unroll
    for (int xx = 0; xx < 7; ++xx) red[wv][xx][co] = acc[xx];
    __syncthreads();
    if (threadIdx.x < 448) {
        int xx = threadIdx.x >> 6, c2 = threadIdx.x & 63;
        float tot = 0.f;
        #pragma unroll
        for (int w = 0; w < 8; ++w) tot += red[w][xx][c2];
        float bnscale = gamma[c2] * rsqrtf(1.f + 1e-5f);
        float h = tot * bnscale + beta[c2];
        float g = 0.5f * h * (1.f + erff(h * 0.70710678118654752440f));
        hmid[((size_t)b * CMID + c2) * KP + y * 7 + xx] = g;
    }
}

// ------ K3: conv3x3 (64->512) + bias + softmax + mix; 512 thr, 2-way cin -----
__global__ __launch_bounds__(512) void conv2_kernel(const float* __restrict__ hmid,
                                                    const float* __restrict__ w2t,
                                                    const float* __restrict__ b2,
                                                    const float* __restrict__ wdyn,
                                                    float* __restrict__ dynw) {
    int y = blockIdx.x, b = blockIdx.y;
    int g = threadIdx.x >> 8, co = threadIdx.x & 255;
    __shared__ float redA[2][7][256];
    __shared__ float redB[2][7][256];
    float a0[7] = {}, a1[7] = {};
    const float* hb = hmid + (size_t)b * CMID * KP;
    for (int ci = 0; ci < 32; ++ci) {
        int cin = g * 32 + ci;
        const float* hrow_base = hb + cin * KP;
        const float* wbase = w2t + (size_t)(cin * 9) * 512 + co;
        #pragma unroll
        for (int ky = 0; ky < 3; ++ky) {
            int iy = y + ky - 1;
            if (0 <= iy && iy < 7) {                    // uniform branch
                float s[9];
                s[0] = 0.f; s[8] = 0.f;
                const float* hr = hrow_base + iy * 7;   // uniform addr -> s_load
                #pragma unroll
                for (int j = 0; j < 7; ++j) s[j + 1] = hr[j];
                const float* wr = wbase + ky * 3 * 512;
                float wa0 = wr[0],    wb0 = wr[256];
                float wa1 = wr[512],  wb1 = wr[768];
                float wa2 = wr[1024], wb2 = wr[1280];
                #pragma unroll
                for (int xx = 0; xx < 7; ++xx) {
                    float v0 = s[xx], v1 = s[xx + 1], v2 = s[xx + 2];
                    a0[xx] += v0 * wa0 + v1 * wa1 + v2 * wa2;
                    a1[xx] += v0 * wb0 + v1 * wb1 + v2 * wb2;
                }
            }
        }
    }
    #pragma unroll
    for (int xx = 0; xx < 7; ++xx) { redA[g][xx][co] = a0[xx]; redB[g][xx][co] = a1[xx]; }
    __syncthreads();
    if (threadIdx.x < 256) {
        int c = threadIdx.x;
        float bias0 = b2[c], bias1 = b2[c + CC];
        const float* wd0 = wdyn + (size_t)c * KP + y * 7;
        const float* wd1 = wdyn + (size_t)(CC + c) * KP + y * 7;
        float* dw = dynw + ((size_t)(b * CC + c)) * KP + y * 7;
        #pragma unroll
        for (int xx = 0; xx < 7; ++xx) {
            float s0 = redA[0][xx][c] + redA[1][xx][c] + bias0;
            float s1 = redB[0][xx][c] + redB[1][xx][c] + bias1;
            float m = fmaxf(s0, s1);
            float e0 = expf(s0 - m), e1 = expf(s1 - m);
            dw[xx] = (e0 * wd0[xx] + e1 * wd1[xx]) / (e0 + e1);
        }
    }
}

// --------- K4: depthwise 7x7: 4 planes/block, wave=plane, 8x8 tiles ----------
// LDS ring layout: padded col d (0..61) of padded row pr stored at word
// (d + 1 + shift(pr)) & 63 within the row's 64-word ring, shift = 4*((pr>>3)&7).
// This makes ds_read_b128 bank groups (2*tx + ty') mod 8 -> near-uniform.
__global__ __launch_bounds__(256) void dwconv_kernel(const float* __restrict__ x,
                                                     const float* __restrict__ dynw,
                                                     float* __restrict__ out) {
    __shared__ float xs[4 * PSZ];           // 62 KB
    int tid = threadIdx.x;
    int g0 = blockIdx.x * 4;                // first plane id of this block

    // zero-fill (covers row pads and ring gaps)
    float4* xs4 = (float4*)xs;
    for (int e = tid; e < 4 * PSZ / 4; e += 256)
        xs4[e] = make_float4(0.f, 0.f, 0.f, 0.f);
    __syncthreads();

    // stage 4 planes: 56 rows x 14 float4 each, rotated ring placement
    for (int idx = tid; idx < 4 * 56 * 14; idx += 256) {
        int p   = idx / 784;
        int rem = idx - p * 784;
        int r   = rem / 14;
        int c4  = rem - r * 14;
        float4 v = *((const float4*)(x + ((size_t)(g0 + p)) * HW + r * WW) + c4);
        int pr    = r + 3;
        int shift = 4 * ((pr >> 3) & 7);
        int col   = (4 * c4 + 4 + shift) & 63;
        *(float4*)(xs + p * PSZ + pr * RSTR + col) = v;
    }
    __syncthreads();

    int wv = tid >> 6, lane = tid & 63;
    int gplane = __builtin_amdgcn_readfirstlane(g0 + wv);   // wave-uniform
    const float* wp = dynw + (size_t)gplane * KP;           // -> s_loads
    float w[49];
    #pragma unroll
    for (int i = 0; i < 49; ++i) w[i] = wp[i];

    if (lane < KP) {
        int ty = lane / 7, tx = lane - ty * 7;
        int r0 = 8 * ty, c0 = 8 * tx;       // output tile origin
        const float* pbase = xs + wv * PSZ;
        float acc[8][8] = {};
        #pragma unroll
        for (int ir = 0; ir < 14; ++ir) {
            int pr = r0 + ir;               // padded row 0..61
            int shift = 4 * ((pr >> 3) & 7);
            const float* rowp = pbase + pr * RSTR;
            float rb[16];
            #pragma unroll
            for (int k = 0; k < 4; ++k) {
                int col = (c0 + shift + 4 * k) & 63;
                float4 v = *(const float4*)(rowp + col);
                rb[4 * k + 0] = v.x; rb[4 * k + 1] = v.y;
                rb[4 * k + 2] = v.z; rb[4 * k + 3] = v.w;
            }
            // rb[i] holds padded col d = c0 + i - 1
            #pragma unroll
            for (int ky = 0; ky < 7; ++ky) {
                int oy = ir - ky;
                if (0 <= oy && oy < 8) {
                    #pragma unroll
                    for (int kx = 0; kx < 7; ++kx) {
                        float ww = w[ky * 7 + kx];
                        #pragma unroll
                        for (int ox = 0; ox < 8; ++ox)
                            acc[oy][ox] += rb[ox + 1 + kx] * ww;
                    }
                }
            }
        }
        float* op = out + (size_t)(g0 + wv) * HW;
        #pragma unroll
        for (int oy = 0; oy < 8; ++oy) {
            float* orow = op + (r0 + oy) * WW + c0;
            *(float4*)(orow)     = make_float4(acc[oy][0], acc[oy][1], acc[oy][2], acc[oy][3]);
            *(float4*)(orow + 4) = make_float4(acc[oy][4], acc[oy][5], acc[oy][6], acc[oy][7]);
        }
    }
}

extern "C" void kernel_launch(void* const* d_in, const int* in_sizes, int n_in,
                              void* d_out, int out_size, void* d_ws, size_t ws_size,
                              hipStream_t stream) {
    const float* x     = (const float*)d_in[0];  // (32,256,56,56)
    const float* wdyn  = (const float*)d_in[1];  // (2,256,7,7)
    const float* w1    = (const float*)d_in[2];  // (64,256,3,3)
    const float* gamma = (const float*)d_in[3];  // (64,)
    const float* beta  = (const float*)d_in[4];  // (64,)
    const float* w2    = (const float*)d_in[5];  // (512,64,3,3)
    const float* b2    = (const float*)d_in[6];  // (512,)
    float* out = (float*)d_out;

    float* ws     = (float*)d_ws;
    float* pooled = ws;               // 401408 floats
    float* hmid   = ws + 401408;      // 100352 floats
    float* dynw   = ws + 501760;      // 401408 floats
    float* w1t    = ws + 903168;      // 147456 floats
    float* w2t    = ws + 1050624;     // 294912 floats  (total 5.2 MB)

    transpose_w_kernel<<<dim3(1152),        256, 0, stream>>>(w1, w2, w1t, w2t);
    pool_kernel       <<<dim3(BB * CC / 4), 256, 0, stream>>>(x, pooled);
    conv1_kernel      <<<dim3(7, BB),       512, 0, stream>>>(pooled, w1t, gamma, beta, hmid);
    conv2_kernel      <<<dim3(7, BB),       512, 0, stream>>>(hmid, w2t, b2, wdyn, dynw);
    dwconv_kernel     <<<dim3(BB * CC / 4), 256, 0, stream>>>(x, dynw, out);
}

// Round 2
// 320.955 us; speedup vs baseline: 1.0080x; 1.0080x over previous
//
#include <hip/hip_runtime.h>
#include <math.h>

#define BB 32
#define CC 256
#define HH 56
#define WW 56
#define KP 49      // 7*7 output pixels of the small convs
#define CMID 64    // C // RED
#define HW 3136    // 56*56

// dwconv LDS plane geometry: 62 padded rows, 64-word ring per row
#define RSTR 64
#define PROWS 62
#define PSZ (PROWS * RSTR)   // 3968 words = 15872 B per plane

// ---- K0: fused  pool (blocks 0..2047)  +  LDS-tiled weight transpose ----
__global__ __launch_bounds__(256) void pre_kernel(const float* __restrict__ x,
                                                  const float* __restrict__ w1,
                                                  const float* __restrict__ w2,
                                                  float* __restrict__ pooled,
                                                  float* __restrict__ w1t,
                                                  float* __restrict__ w2t) {
    int bid = blockIdx.x;
    if (bid < 2048) {
        // pool: 4 planes per block, wave = plane, lane = 7x7 output window
        int wv = threadIdx.x >> 6, lane = threadIdx.x & 63;
        int g = bid * 4 + wv;               // plane id = b*256 + c
        if (lane < KP) {
            int ko = lane / 7, kw = lane - ko * 7;
            const float* base = x + (size_t)g * HW + (ko * 8) * WW + kw * 8;
            float s = 0.f;
            #pragma unroll
            for (int r = 0; r < 8; ++r) {
                float4 a = *(const float4*)(base + r * WW);
                float4 b4 = *(const float4*)(base + r * WW + 4);
                s += a.x + a.y + a.z + a.w + b4.x + b4.y + b4.z + b4.w;
            }
            pooled[(size_t)g * KP + lane] = s * (1.f / 64.f);
        }
        return;
    }
    // LDS-tiled transpose: coalesced read AND write (65-float stride = no conflicts)
    __shared__ float t[64][65];
    int r = threadIdx.x >> 6, c = threadIdx.x & 63;
    if (bid < 2048 + 36) {                  // w1: (64co, 2304ct) -> w1t (2304, 64)
        int ct0 = (bid - 2048) * 64;
        #pragma unroll
        for (int i = 0; i < 16; ++i)
            t[r + 4 * i][c] = w1[(size_t)(r + 4 * i) * 2304 + ct0 + c];
        __syncthreads();
        #pragma unroll
        for (int i = 0; i < 16; ++i)
            w1t[(size_t)(ct0 + r + 4 * i) * 64 + c] = t[c][r + 4 * i];
    } else {                                // w2: (512co, 576ct) -> w2t (576, 512)
        int tt = bid - 2048 - 36;
        int co0 = (tt / 9) * 64, ct0 = (tt % 9) * 64;
        #pragma unroll
        for (int i = 0; i < 16; ++i)
            t[r + 4 * i][c] = w2[(size_t)(co0 + r + 4 * i) * 576 + ct0 + c];
        __syncthreads();
        #pragma unroll
        for (int i = 0; i < 16; ++i)
            w2t[(size_t)(ct0 + r + 4 * i) * 512 + co0 + c] = t[c][r + 4 * i];
    }
}

// ------------- K2: conv3x3 (256->64) + BN + exact GELU; 512 thr, 8-way cin ---
__global__ __launch_bounds__(512) void conv1_kernel(const float* __restrict__ pooled,
                                                    const float* __restrict__ w1t,
                                                    const float* __restrict__ gamma,
                                                    const float* __restrict__ beta,
                                                    float* __restrict__ hmid) {
    int y = blockIdx.x, b = blockIdx.y;
    int wv = threadIdx.x >> 6, co = threadIdx.x & 63;
    __shared__ float red[8][7][64];
    float acc[7] = {0.f, 0.f, 0.f, 0.f, 0.f, 0.f, 0.f};
    const float* pb = pooled + (size_t)b * CC * KP;
    for (int ci = 0; ci < 32; ++ci) {
        int cin = wv * 32 + ci;
        const float* prow_base = pb + cin * KP;
        const float* wbase = w1t + (size_t)(cin * 9) * 64 + co;
        #pragma unroll
        for (int ky = 0; ky < 3; ++ky) {
            int iy = y + ky - 1;
            if (0 <= iy && iy < 7) {                    // uniform branch
                float s[9];
                s[0] = 0.f; s[8] = 0.f;
                const float* pr = prow_base + iy * 7;   // uniform addr -> s_load
                #pragma unroll
                for (int j = 0; j < 7; ++j) s[j + 1] = pr[j];
                const float* wr = wbase + ky * 3 * 64;
                float w0 = wr[0], w1v = wr[64], w2v = wr[128];
                #pragma unroll
                for (int xx = 0; xx < 7; ++xx)
                    acc[xx] += s[xx] * w0 + s[xx + 1] * w1v + s[xx + 2] * w2v;
            }
        }
    }
    #pragma unroll
    for (int xx = 0; xx < 7; ++xx) red[wv][xx][co] = acc[xx];
    __syncthreads();
    if (threadIdx.x < 448) {
        int xx = threadIdx.x >> 6, c2 = threadIdx.x & 63;
        float tot = 0.f;
        #pragma unroll
        for (int w = 0; w < 8; ++w) tot += red[w][xx][c2];
        float bnscale = gamma[c2] * rsqrtf(1.f + 1e-5f);
        float h = tot * bnscale + beta[c2];
        float g = 0.5f * h * (1.f + erff(h * 0.70710678118654752440f));
        hmid[((size_t)b * CMID + c2) * KP + y * 7 + xx] = g;
    }
}

// ------ K3: conv3x3 (64->512) + bias + softmax + mix; 512 thr, 2-way cin -----
__global__ __launch_bounds__(512) void conv2_kernel(const float* __restrict__ hmid,
                                                    const float* __restrict__ w2t,
                                                    const float* __restrict__ b2,
                                                    const float* __restrict__ wdyn,
                                                    float* __restrict__ dynw) {
    int y = blockIdx.x, b = blockIdx.y;
    int g = threadIdx.x >> 8, co = threadIdx.x & 255;
    __shared__ float redA[2][7][256];
    __shared__ float redB[2][7][256];
    float a0[7] = {}, a1[7] = {};
    const float* hb = hmid + (size_t)b * CMID * KP;
    for (int ci = 0; ci < 32; ++ci) {
        int cin = g * 32 + ci;
        const float* hrow_base = hb + cin * KP;
        const float* wbase = w2t + (size_t)(cin * 9) * 512 + co;
        #pragma unroll
        for (int ky = 0; ky < 3; ++ky) {
            int iy = y + ky - 1;
            if (0 <= iy && iy < 7) {                    // uniform branch
                float s[9];
                s[0] = 0.f; s[8] = 0.f;
                const float* hr = hrow_base + iy * 7;   // uniform addr -> s_load
                #pragma unroll
                for (int j = 0; j < 7; ++j) s[j + 1] = hr[j];
                const float* wr = wbase + ky * 3 * 512;
                float wa0 = wr[0],    wb0 = wr[256];
                float wa1 = wr[512],  wb1 = wr[768];
                float wa2 = wr[1024], wb2 = wr[1280];
                #pragma unroll
                for (int xx = 0; xx < 7; ++xx) {
                    float v0 = s[xx], v1 = s[xx + 1], v2 = s[xx + 2];
                    a0[xx] += v0 * wa0 + v1 * wa1 + v2 * wa2;
                    a1[xx] += v0 * wb0 + v1 * wb1 + v2 * wb2;
                }
            }
        }
    }
    #pragma unroll
    for (int xx = 0; xx < 7; ++xx) { redA[g][xx][co] = a0[xx]; redB[g][xx][co] = a1[xx]; }
    __syncthreads();
    if (threadIdx.x < 256) {
        int c = threadIdx.x;
        float bias0 = b2[c], bias1 = b2[c + CC];
        const float* wd0 = wdyn + (size_t)c * KP + y * 7;
        const float* wd1 = wdyn + (size_t)(CC + c) * KP + y * 7;
        float* dw = dynw + ((size_t)(b * CC + c)) * KP + y * 7;
        #pragma unroll
        for (int xx = 0; xx < 7; ++xx) {
            float s0 = redA[0][xx][c] + redA[1][xx][c] + bias0;
            float s1 = redB[0][xx][c] + redB[1][xx][c] + bias1;
            float m = fmaxf(s0, s1);
            float e0 = expf(s0 - m), e1 = expf(s1 - m);
            dw[xx] = (e0 * wd0[xx] + e1 * wd1[xx]) / (e0 + e1);
        }
    }
}

// --------- K4: depthwise 7x7: ONE plane / ONE wave / 64-thread blocks --------
// 15.5 KB LDS per block -> 10 blocks/CU (was 2), independent waves, no
// inter-wave barriers. Tiles: 8x7 grid of 7-row x 8-col tiles -> 56/64 lanes.
// Ring shift = 4*(pr&7): with pr = 7*ty + ir, bank-group residues of the 4
// ds_read_b128 are exactly uniform (7 lanes per 4-bank group).
__global__ __launch_bounds__(64, 4) void dwconv_kernel(const float* __restrict__ x,
                                                       const float* __restrict__ dynw,
                                                       float* __restrict__ out) {
    __shared__ __align__(16) float xs[PSZ];     // 15872 B
    int tid = threadIdx.x;
    int g = blockIdx.x;                          // plane id = b*256 + c

    // 49 weights via uniform address -> s_loads, issued first (latency overlap)
    const float* wp = dynw + (size_t)g * KP;
    float w[49];
    #pragma unroll
    for (int i = 0; i < 49; ++i) w[i] = wp[i];

    // zero ONLY pads: 6 full pad rows (16 f4) + 2 side chunks per data row.
    // Data words per row are (shift+4 .. shift+59): disjoint from the two
    // side chunks (shift+0..3, shift+60..63) -> no barrier needed vs staging.
    for (int idx = tid; idx < 208; idx += 64) {
        int pr, col;
        if (idx < 96) {
            int rowi = idx >> 4, c4 = idx & 15;
            pr = rowi < 3 ? rowi : rowi + 56;    // rows 0,1,2,59,60,61
            col = 4 * c4;
        } else {
            int i = idx - 96;
            int rr = i >> 1;
            pr = rr + 3;
            int shift = 4 * (pr & 7);
            col = (i & 1) ? ((shift + 60) & 63) : shift;
        }
        *(float4*)(xs + pr * RSTR + col) = make_float4(0.f, 0.f, 0.f, 0.f);
    }

    // stage plane: 56 rows x 14 float4, rotated ring placement
    for (int idx = tid; idx < 784; idx += 64) {
        int rr = idx / 14, c4 = idx - rr * 14;
        float4 v = *((const float4*)(x + (size_t)g * HW + rr * WW) + c4);
        int pr = rr + 3;
        int shift = 4 * (pr & 7);
        int col = (4 * c4 + 4 + shift) & 63;     // padded col d at word (d+1+shift)&63
        *(float4*)(xs + pr * RSTR + col) = v;
    }
    __syncthreads();                             // single-wave block: cheap

    if (tid < 56) {
        int ty = tid / 7, tx = tid - ty * 7;     // ty 0..7, tx 0..6
        int r0 = 7 * ty, c0 = 8 * tx;            // 7-row x 8-col output tile
        float acc[7][8] = {};
        #pragma unroll
        for (int ir = 0; ir < 13; ++ir) {
            int pr = r0 + ir;                    // padded row 0..61
            int shift = 4 * (pr & 7);
            const float* rowp = xs + pr * RSTR;
            float rb[16];                        // rb[i] = padded col c0-1+i
            #pragma unroll
            for (int k = 0; k < 4; ++k) {
                int col = (c0 + shift + 4 * k) & 63;
                float4 v = *(const float4*)(rowp + col);
                rb[4 * k + 0] = v.x; rb[4 * k + 1] = v.y;
                rb[4 * k + 2] = v.z; rb[4 * k + 3] = v.w;
            }
            #pragma unroll
            for (int ky = 0; ky < 7; ++ky) {
                int oy = ir - ky;
                if (0 <= oy && oy < 7) {
                    #pragma unroll
                    for (int kx = 0; kx < 7; ++kx) {
                        float ww = w[ky * 7 + kx];
                        #pragma unroll
                        for (int ox = 0; ox < 8; ++ox)
                            acc[oy][ox] += rb[ox + 1 + kx] * ww;
                    }
                }
            }
        }
        float* op = out + (size_t)g * HW;
        #pragma unroll
        for (int oy = 0; oy < 7; ++oy) {
            float* orow = op + (r0 + oy) * WW + c0;
            *(float4*)(orow)     = make_float4(acc[oy][0], acc[oy][1], acc[oy][2], acc[oy][3]);
            *(float4*)(orow + 4) = make_float4(acc[oy][4], acc[oy][5], acc[oy][6], acc[oy][7]);
        }
    }
}

extern "C" void kernel_launch(void* const* d_in, const int* in_sizes, int n_in,
                              void* d_out, int out_size, void* d_ws, size_t ws_size,
                              hipStream_t stream) {
    const float* x     = (const float*)d_in[0];  // (32,256,56,56)
    const float* wdyn  = (const float*)d_in[1];  // (2,256,7,7)
    const float* w1    = (const float*)d_in[2];  // (64,256,3,3)
    const float* gamma = (const float*)d_in[3];  // (64,)
    const float* beta  = (const float*)d_in[4];  // (64,)
    const float* w2    = (const float*)d_in[5];  // (512,64,3,3)
    const float* b2    = (const float*)d_in[6];  // (512,)
    float* out = (float*)d_out;

    float* ws     = (float*)d_ws;
    float* pooled = ws;               // 401408 floats
    float* hmid   = ws + 401408;      // 100352 floats
    float* dynw   = ws + 501760;      // 401408 floats
    float* w1t    = ws + 903168;      // 147456 floats
    float* w2t    = ws + 1050624;     // 294912 floats  (total 5.2 MB)

    pre_kernel   <<<dim3(2048 + 36 + 72), 256, 0, stream>>>(x, w1, w2, pooled, w1t, w2t);
    conv1_kernel <<<dim3(7, BB),          512, 0, stream>>>(pooled, w1t, gamma, beta, hmid);
    conv2_kernel <<<dim3(7, BB),          512, 0, stream>>>(hmid, w2t, b2, wdyn, dynw);
    dwconv_kernel<<<dim3(BB * CC),         64, 0, stream>>>(x, dynw, out);
}

// Round 3
// 282.152 us; speedup vs baseline: 1.1466x; 1.1375x over previous
//
#include <hip/hip_runtime.h>
#include <math.h>

#define BB 32
#define CC 256
#define HH 56
#define WW 56
#define KP 49      // 7*7 output pixels of the small convs
#define CMID 64    // C // RED
#define HW 3136    // 56*56

// ---- K0: fused  pool (blocks 0..2047)  +  LDS-tiled weight transpose ----
__global__ __launch_bounds__(256) void pre_kernel(const float* __restrict__ x,
                                                  const float* __restrict__ w1,
                                                  const float* __restrict__ w2,
                                                  float* __restrict__ pooled,
                                                  float* __restrict__ w1t,
                                                  float* __restrict__ w2t) {
    int bid = blockIdx.x;
    if (bid < 2048) {
        // pool: 4 planes per block, wave = plane, lane = 7x7 output window
        int wv = threadIdx.x >> 6, lane = threadIdx.x & 63;
        int g = bid * 4 + wv;               // plane id = b*256 + c
        if (lane < KP) {
            int ko = lane / 7, kw = lane - ko * 7;
            const float* base = x + (size_t)g * HW + (ko * 8) * WW + kw * 8;
            float s = 0.f;
            #pragma unroll
            for (int r = 0; r < 8; ++r) {
                float4 a = *(const float4*)(base + r * WW);
                float4 b4 = *(const float4*)(base + r * WW + 4);
                s += a.x + a.y + a.z + a.w + b4.x + b4.y + b4.z + b4.w;
            }
            pooled[(size_t)g * KP + lane] = s * (1.f / 64.f);
        }
        return;
    }
    // LDS-tiled transpose: coalesced read AND write (65-float stride = no conflicts)
    __shared__ float t[64][65];
    int r = threadIdx.x >> 6, c = threadIdx.x & 63;
    if (bid < 2048 + 36) {                  // w1: (64co, 2304ct) -> w1t (2304, 64)
        int ct0 = (bid - 2048) * 64;
        #pragma unroll
        for (int i = 0; i < 16; ++i)
            t[r + 4 * i][c] = w1[(size_t)(r + 4 * i) * 2304 + ct0 + c];
        __syncthreads();
        #pragma unroll
        for (int i = 0; i < 16; ++i)
            w1t[(size_t)(ct0 + r + 4 * i) * 64 + c] = t[c][r + 4 * i];
    } else {                                // w2: (512co, 576ct) -> w2t (576, 512)
        int tt = bid - 2048 - 36;
        int co0 = (tt / 9) * 64, ct0 = (tt % 9) * 64;
        #pragma unroll
        for (int i = 0; i < 16; ++i)
            t[r + 4 * i][c] = w2[(size_t)(co0 + r + 4 * i) * 576 + ct0 + c];
        __syncthreads();
        #pragma unroll
        for (int i = 0; i < 16; ++i)
            w2t[(size_t)(ct0 + r + 4 * i) * 512 + co0 + c] = t[c][r + 4 * i];
    }
}

// --- K2: conv3x3 (256->64) + BN + GELU; 1024 thr = 16 waves x 16 cins -------
__global__ __launch_bounds__(1024) void conv1_kernel(const float* __restrict__ pooled,
                                                     const float* __restrict__ w1t,
                                                     const float* __restrict__ gamma,
                                                     const float* __restrict__ beta,
                                                     float* __restrict__ hmid) {
    int y = blockIdx.x, b = blockIdx.y;
    int wv = threadIdx.x >> 6, co = threadIdx.x & 63;
    __shared__ float red[16][7][64];
    float acc[7] = {0.f, 0.f, 0.f, 0.f, 0.f, 0.f, 0.f};
    const float* pb = pooled + (size_t)b * CC * KP;
    int cin0 = __builtin_amdgcn_readfirstlane(wv * 16);   // scalar row addressing
    #pragma unroll 4
    for (int ci = 0; ci < 16; ++ci) {
        int cin = cin0 + ci;
        const float* prow_base = pb + cin * KP;
        const float* wbase = w1t + (size_t)(cin * 9) * 64 + co;
        #pragma unroll
        for (int ky = 0; ky < 3; ++ky) {
            int iy = y + ky - 1;
            if (0 <= iy && iy < 7) {                    // uniform branch
                float s[9];
                s[0] = 0.f; s[8] = 0.f;
                const float* pr = prow_base + iy * 7;   // uniform addr -> s_load
                #pragma unroll
                for (int j = 0; j < 7; ++j) s[j + 1] = pr[j];
                const float* wr = wbase + ky * 3 * 64;
                float w0 = wr[0], w1v = wr[64], w2v = wr[128];
                #pragma unroll
                for (int xx = 0; xx < 7; ++xx)
                    acc[xx] += s[xx] * w0 + s[xx + 1] * w1v + s[xx + 2] * w2v;
            }
        }
    }
    #pragma unroll
    for (int xx = 0; xx < 7; ++xx) red[wv][xx][co] = acc[xx];
    __syncthreads();
    if (threadIdx.x < 448) {
        int xx = threadIdx.x >> 6, c2 = threadIdx.x & 63;
        float tot = 0.f;
        #pragma unroll
        for (int w = 0; w < 16; ++w) tot += red[w][xx][c2];
        float bnscale = gamma[c2] * rsqrtf(1.f + 1e-5f);
        float h = tot * bnscale + beta[c2];
        float g = 0.5f * h * (1.f + erff(h * 0.70710678118654752440f));
        hmid[((size_t)b * CMID + c2) * KP + y * 7 + xx] = g;
    }
}

// -- K3: conv3x3 (64->512) + bias + softmax + mix; 1024 thr = 4 qtr x 256 co -
__global__ __launch_bounds__(1024) void conv2_kernel(const float* __restrict__ hmid,
                                                     const float* __restrict__ w2t,
                                                     const float* __restrict__ b2,
                                                     const float* __restrict__ wdyn,
                                                     float* __restrict__ dynw) {
    int y = blockIdx.x, b = blockIdx.y;
    int qq = threadIdx.x >> 8, co = threadIdx.x & 255;
    __shared__ float redA[4][7][256];
    __shared__ float redB[4][7][256];
    float a0[7] = {}, a1[7] = {};
    const float* hb = hmid + (size_t)b * CMID * KP;
    int cin0 = __builtin_amdgcn_readfirstlane(qq * 16);   // scalar row addressing
    #pragma unroll 2
    for (int ci = 0; ci < 16; ++ci) {
        int cin = cin0 + ci;
        const float* hrow_base = hb + cin * KP;
        const float* wbase = w2t + (size_t)(cin * 9) * 512 + co;
        #pragma unroll
        for (int ky = 0; ky < 3; ++ky) {
            int iy = y + ky - 1;
            if (0 <= iy && iy < 7) {                    // uniform branch
                float s[9];
                s[0] = 0.f; s[8] = 0.f;
                const float* hr = hrow_base + iy * 7;   // uniform addr -> s_load
                #pragma unroll
                for (int j = 0; j < 7; ++j) s[j + 1] = hr[j];
                const float* wr = wbase + ky * 3 * 512;
                float wa0 = wr[0],    wb0 = wr[256];
                float wa1 = wr[512],  wb1 = wr[768];
                float wa2 = wr[1024], wb2 = wr[1280];
                #pragma unroll
                for (int xx = 0; xx < 7; ++xx) {
                    float v0 = s[xx], v1 = s[xx + 1], v2 = s[xx + 2];
                    a0[xx] += v0 * wa0 + v1 * wa1 + v2 * wa2;
                    a1[xx] += v0 * wb0 + v1 * wb1 + v2 * wb2;
                }
            }
        }
    }
    #pragma unroll
    for (int xx = 0; xx < 7; ++xx) { redA[qq][xx][co] = a0[xx]; redB[qq][xx][co] = a1[xx]; }
    __syncthreads();
    if (threadIdx.x < 256) {
        int c = threadIdx.x;
        float bias0 = b2[c], bias1 = b2[c + CC];
        const float* wd0 = wdyn + (size_t)c * KP + y * 7;
        const float* wd1 = wdyn + (size_t)(CC + c) * KP + y * 7;
        float* dw = dynw + ((size_t)(b * CC + c)) * KP + y * 7;
        #pragma unroll
        for (int xx = 0; xx < 7; ++xx) {
            float s0 = redA[0][xx][c] + redA[1][xx][c] + redA[2][xx][c] + redA[3][xx][c] + bias0;
            float s1 = redB[0][xx][c] + redB[1][xx][c] + redB[2][xx][c] + redB[3][xx][c] + bias1;
            float m = fmaxf(s0, s1);
            float e0 = expf(s0 - m), e1 = expf(s1 - m);
            dw[xx] = (e0 * wd0[xx] + e1 * wd1[xx]) / (e0 + e1);
        }
    }
}

// --------- K4: depthwise 7x7, NO LDS: direct predicated global reads --------
// Per output tile row we need data cols c0-3 .. c0+10; c0 = 8*tx, so the
// 4 aligned float4 chunks starting at word 8*tx-4 cover exactly that, and
// each chunk is either fully in-bounds or fully pad (56 % 4 == 0).
// x is L3-resident (written-through by pre_kernel's pool read). LDS = 0,
// no barrier, no staging, no bank conflicts; weights via s_load (uniform g).
__global__ __launch_bounds__(64, 4) void dwconv_kernel(const float* __restrict__ x,
                                                       const float* __restrict__ dynw,
                                                       float* __restrict__ out) {
    int tid = threadIdx.x;
    int g = blockIdx.x;                          // plane id = b*256 + c

    const float* wp = dynw + (size_t)g * KP;     // uniform -> s_load_dwordx16
    float w[49];
    #pragma unroll
    for (int i = 0; i < 49; ++i) w[i] = wp[i];

    if (tid < 56) {
        int ty = tid / 7, tx = tid - ty * 7;     // ty 0..7, tx 0..6
        int r0 = 7 * ty, c0 = 8 * tx;            // 7-row x 8-col output tile
        const float* xp = x + (size_t)g * HW;
        float acc[7][8] = {};
        #pragma unroll
        for (int ir = 0; ir < 13; ++ir) {
            int r = r0 + ir - 3;                 // data row, may be OOB
            bool rowok = (unsigned)r < 56u;
            int rbase = r * WW;
            float rb[16];                        // rb[j] = data col c0-4+j
            #pragma unroll
            for (int k = 0; k < 4; ++k) {
                int w0 = c0 - 4 + 4 * k;
                bool ok = rowok & ((unsigned)w0 < 56u);
                int off = ok ? (rbase + w0) : 0; // safe dummy addr when pad
                float4 v = *(const float4*)(xp + off);
                if (!ok) v = make_float4(0.f, 0.f, 0.f, 0.f);
                rb[4 * k + 0] = v.x; rb[4 * k + 1] = v.y;
                rb[4 * k + 2] = v.z; rb[4 * k + 3] = v.w;
            }
            #pragma unroll
            for (int ky = 0; ky < 7; ++ky) {
                int oy = ir - ky;
                if (0 <= oy && oy < 7) {
                    #pragma unroll
                    for (int kx = 0; kx < 7; ++kx) {
                        float ww = w[ky * 7 + kx];
                        #pragma unroll
                        for (int ox = 0; ox < 8; ++ox)
                            acc[oy][ox] += rb[ox + 1 + kx] * ww;
                    }
                }
            }
        }
        float* op = out + (size_t)g * HW;
        #pragma unroll
        for (int oy = 0; oy < 7; ++oy) {
            float* orow = op + (r0 + oy) * WW + c0;
            *(float4*)(orow)     = make_float4(acc[oy][0], acc[oy][1], acc[oy][2], acc[oy][3]);
            *(float4*)(orow + 4) = make_float4(acc[oy][4], acc[oy][5], acc[oy][6], acc[oy][7]);
        }
    }
}

extern "C" void kernel_launch(void* const* d_in, const int* in_sizes, int n_in,
                              void* d_out, int out_size, void* d_ws, size_t ws_size,
                              hipStream_t stream) {
    const float* x     = (const float*)d_in[0];  // (32,256,56,56)
    const float* wdyn  = (const float*)d_in[1];  // (2,256,7,7)
    const float* w1    = (const float*)d_in[2];  // (64,256,3,3)
    const float* gamma = (const float*)d_in[3];  // (64,)
    const float* beta  = (const float*)d_in[4];  // (64,)
    const float* w2    = (const float*)d_in[5];  // (512,64,3,3)
    const float* b2    = (const float*)d_in[6];  // (512,)
    float* out = (float*)d_out;

    float* ws     = (float*)d_ws;
    float* pooled = ws;               // 401408 floats
    float* hmid   = ws + 401408;      // 100352 floats
    float* dynw   = ws + 501760;      // 401408 floats
    float* w1t    = ws + 903168;      // 147456 floats
    float* w2t    = ws + 1050624;     // 294912 floats  (total 5.2 MB)

    pre_kernel   <<<dim3(2048 + 36 + 72),  256, 0, stream>>>(x, w1, w2, pooled, w1t, w2t);
    conv1_kernel <<<dim3(7, BB),          1024, 0, stream>>>(pooled, w1t, gamma, beta, hmid);
    conv2_kernel <<<dim3(7, BB),          1024, 0, stream>>>(hmid, w2t, b2, wdyn, dynw);
    dwconv_kernel<<<dim3(BB * CC),          64, 0, stream>>>(x, dynw, out);
}